// Round 3
// baseline (1895.555 us; speedup 1.0000x reference)
//
#include <hip/hip_runtime.h>

#define N_NODES    1000000
#define N_EDGES    32000000
#define NUM_GRAPHS 1024
#define NCOPIES    8   // one agg copy per XCD

// s_getreg immediate: size=32 (field [15:11]=31), offset=0, id=20 (HW_REG_XCC_ID, gfx940+)
#define HWREG_XCC_ID ((31u << 11) | 20u)

typedef int vint4 __attribute__((ext_vector_type(4)));  // native vector: OK for nontemporal builtin

// ---------------------------------------------------------------------------
// Stage 1a (fast path): agg_copy[xcd][dst[e]] += x[src[e]].
// Workgroup-scope atomics stay in the local XCD's TCC (no memory-side RMW);
// each copy is touched only by its own XCD, so L2-local atomics are coherent
// for that copy. Kernel-end release writes dirty lines back for stage 2.
// Edge reads are non-temporal so the 256 MB stream doesn't evict agg from L2.
// ---------------------------------------------------------------------------
__global__ void scatter_edges_xcd(const vint4* __restrict__ src4,
                                  const vint4* __restrict__ dst4,
                                  const float* __restrict__ x,
                                  float* __restrict__ aggs) {
    int t = blockIdx.x * blockDim.x + threadIdx.x;
    unsigned xcc = __builtin_amdgcn_s_getreg(HWREG_XCC_ID) & (NCOPIES - 1);
    float* agg = aggs + (size_t)xcc * N_NODES;
    if (t < N_EDGES / 4) {
        vint4 s = __builtin_nontemporal_load(&src4[t]);
        vint4 d = __builtin_nontemporal_load(&dst4[t]);
        float x0 = x[s.x];
        float x1 = x[s.y];
        float x2 = x[s.z];
        float x3 = x[s.w];
        __hip_atomic_fetch_add(&agg[d.x], x0, __ATOMIC_RELAXED, __HIP_MEMORY_SCOPE_WORKGROUP);
        __hip_atomic_fetch_add(&agg[d.y], x1, __ATOMIC_RELAXED, __HIP_MEMORY_SCOPE_WORKGROUP);
        __hip_atomic_fetch_add(&agg[d.z], x2, __ATOMIC_RELAXED, __HIP_MEMORY_SCOPE_WORKGROUP);
        __hip_atomic_fetch_add(&agg[d.w], x3, __ATOMIC_RELAXED, __HIP_MEMORY_SCOPE_WORKGROUP);
    }
}

// Stage 1b (fallback if ws too small): single copy, device-scope atomics.
__global__ void scatter_edges_dev(const vint4* __restrict__ src4,
                                  const vint4* __restrict__ dst4,
                                  const float* __restrict__ x,
                                  float* __restrict__ agg) {
    int t = blockIdx.x * blockDim.x + threadIdx.x;
    if (t < N_EDGES / 4) {
        vint4 s = __builtin_nontemporal_load(&src4[t]);
        vint4 d = __builtin_nontemporal_load(&dst4[t]);
        atomicAdd(&agg[d.x], x[s.x]);
        atomicAdd(&agg[d.y], x[s.y]);
        atomicAdd(&agg[d.z], x[s.z]);
        atomicAdd(&agg[d.w], x[s.w]);
    }
}

// ---------------------------------------------------------------------------
// Stage 2: sum the copies, relu, segment-sum into per-graph bins.
// batch is sorted -> almost every 64-lane wave is graph-uniform:
// wave shuffle-reduce + 1 atomic per wave; boundary waves fall back per-lane.
// ---------------------------------------------------------------------------
__global__ void pool_nodes_kernel(const float* __restrict__ aggs,
                                  int ncopies,
                                  const int* __restrict__ batch,
                                  float* __restrict__ sums,
                                  float* __restrict__ counts) {
    int i = blockIdx.x * blockDim.x + threadIdx.x;
    float h = 0.0f;
    int g = -1;
    if (i < N_NODES) {
        float a = 0.0f;
        for (int c = 0; c < ncopies; ++c)
            a += aggs[(size_t)c * N_NODES + i];
        h = fmaxf(a, 0.0f);
        g = batch[i];
    }
    int g0 = __shfl(g, 0);            // wave-wide (64 lanes)
    if (__all(g == g0)) {
        #pragma unroll
        for (int off = 32; off > 0; off >>= 1)
            h += __shfl_down(h, off);
        if ((threadIdx.x & 63) == 0 && g0 >= 0) {
            atomicAdd(&sums[g0], h);
            atomicAdd(&counts[g0], 64.0f);
        }
    } else {
        if (g >= 0) {
            atomicAdd(&sums[g], h);
            atomicAdd(&counts[g], 1.0f);
        }
    }
}

// Stage 3: out[g] = (sums[g] / max(counts[g],1)) * W + b
__global__ void finalize_kernel(const float* __restrict__ sums,
                                const float* __restrict__ counts,
                                const float* __restrict__ W,
                                const float* __restrict__ b,
                                float* __restrict__ out) {
    int g = blockIdx.x * blockDim.x + threadIdx.x;
    if (g < NUM_GRAPHS) {
        float pooled = sums[g] / fmaxf(counts[g], 1.0f);
        out[g] = pooled * W[0] + b[0];
    }
}

extern "C" void kernel_launch(void* const* d_in, const int* in_sizes, int n_in,
                              void* d_out, int out_size, void* d_ws, size_t ws_size,
                              hipStream_t stream) {
    const float* x     = (const float*)d_in[0];
    const float* W     = (const float*)d_in[1];
    const float* b     = (const float*)d_in[2];
    const int*   edge  = (const int*)d_in[3];   // [2, N_EDGES] int32
    const int*   batch = (const int*)d_in[4];   // [N_NODES] int32, sorted
    float* out = (float*)d_out;

    const size_t repl_floats = (size_t)NCOPIES * N_NODES + 2 * NUM_GRAPHS;
    const bool   use_repl    = ws_size >= repl_floats * sizeof(float);
    const int    ncopies     = use_repl ? NCOPIES : 1;

    // Workspace: agg[ncopies][N_NODES] | sums[NUM_GRAPHS] | counts[NUM_GRAPHS]
    float* aggs   = (float*)d_ws;
    float* sums   = aggs + (size_t)ncopies * N_NODES;
    float* counts = sums + NUM_GRAPHS;

    (void)hipMemsetAsync(d_ws, 0,
                         ((size_t)ncopies * N_NODES + 2 * NUM_GRAPHS) * sizeof(float),
                         stream);

    const int* src = edge;             // row 0
    const int* dst = edge + N_EDGES;   // row 1

    {
        int nthreads = N_EDGES / 4;
        int block = 256;
        int grid = (nthreads + block - 1) / block;
        if (use_repl)
            scatter_edges_xcd<<<grid, block, 0, stream>>>(
                (const vint4*)src, (const vint4*)dst, x, aggs);
        else
            scatter_edges_dev<<<grid, block, 0, stream>>>(
                (const vint4*)src, (const vint4*)dst, x, aggs);
    }
    {
        int block = 256;
        int grid = (N_NODES + block - 1) / block;
        pool_nodes_kernel<<<grid, block, 0, stream>>>(aggs, ncopies, batch, sums, counts);
    }
    {
        int block = 256;
        int grid = (NUM_GRAPHS + block - 1) / block;
        finalize_kernel<<<grid, block, 0, stream>>>(sums, counts, W, b, out);
    }
}

// Round 4
// 785.278 us; speedup vs baseline: 2.4139x; 2.4139x over previous
//
#include <hip/hip_runtime.h>

#define N_NODES    1000000
#define N_EDGES    32000000
#define NUM_GRAPHS 1024
#define NCOPIES    8   // fallback path: one agg copy per XCD

#define HWREG_XCC_ID ((31u << 11) | 20u)

// ---- binning parameters -----------------------------------------------------
#define BUCKET_SHIFT 12
#define BUCKET_NODES (1 << BUCKET_SHIFT)          // 4096 nodes per bucket
#define NBUCKETS     245                          // ceil(1e6 / 4096)
#define CAP          136192                       // slots/bucket: mean 131072 + ~14 sigma, %4==0
#define NCHUNK       512
#define EDGES_PER_CHUNK (N_EDGES / NCHUNK)        // 62500 (exact)

typedef int          vint4  __attribute__((ext_vector_type(4)));
typedef unsigned int uint32;
typedef unsigned int vuint4 __attribute__((ext_vector_type(4)));

// ---------------------------------------------------------------------------
// Phase 1: bin edges by dst-bucket. Per WG: LDS histogram of its chunk,
// one global atomic per (WG,bucket) to reserve a slot block, then re-stream
// and store packed (dst_local<<20 | src) u32 into the reserved slots.
// No per-edge global atomics.
// ---------------------------------------------------------------------------
__global__ __launch_bounds__(1024)
void bucket_scatter(const int* __restrict__ src,
                    const int* __restrict__ dst,
                    uint32* __restrict__ sorted,
                    uint32* __restrict__ gpos) {
    __shared__ uint32 hist[NBUCKETS];
    __shared__ uint32 pos[NBUCKETS];
    const int tid = threadIdx.x;
    const size_t base = (size_t)blockIdx.x * EDGES_PER_CHUNK;

    for (int b = tid; b < NBUCKETS; b += 1024) hist[b] = 0;
    __syncthreads();

    const vint4* d4 = (const vint4*)(dst + base);   // 62500 % 4 == 0 -> 16B aligned
    const vint4* s4 = (const vint4*)(src + base);
    const int nvec = EDGES_PER_CHUNK / 4;           // 15625

    for (int i = tid; i < nvec; i += 1024) {
        vint4 d = d4[i];
        atomicAdd(&hist[(uint32)d.x >> BUCKET_SHIFT], 1u);
        atomicAdd(&hist[(uint32)d.y >> BUCKET_SHIFT], 1u);
        atomicAdd(&hist[(uint32)d.z >> BUCKET_SHIFT], 1u);
        atomicAdd(&hist[(uint32)d.w >> BUCKET_SHIFT], 1u);
    }
    __syncthreads();

    for (int b = tid; b < NBUCKETS; b += 1024)
        pos[b] = atomicAdd(&gpos[b], hist[b]);      // block reservation (125K atomics total)
    __syncthreads();

    for (int i = tid; i < nvec; i += 1024) {
        vint4 d = d4[i];
        vint4 s = s4[i];
        {
            uint32 dd = (uint32)d.x, b = dd >> BUCKET_SHIFT, dl = dd & (BUCKET_NODES - 1);
            uint32 slot = atomicAdd(&pos[b], 1u);
            if (slot < CAP) sorted[(size_t)b * CAP + slot] = (dl << 20) | (uint32)s.x;
        }
        {
            uint32 dd = (uint32)d.y, b = dd >> BUCKET_SHIFT, dl = dd & (BUCKET_NODES - 1);
            uint32 slot = atomicAdd(&pos[b], 1u);
            if (slot < CAP) sorted[(size_t)b * CAP + slot] = (dl << 20) | (uint32)s.y;
        }
        {
            uint32 dd = (uint32)d.z, b = dd >> BUCKET_SHIFT, dl = dd & (BUCKET_NODES - 1);
            uint32 slot = atomicAdd(&pos[b], 1u);
            if (slot < CAP) sorted[(size_t)b * CAP + slot] = (dl << 20) | (uint32)s.z;
        }
        {
            uint32 dd = (uint32)d.w, b = dd >> BUCKET_SHIFT, dl = dd & (BUCKET_NODES - 1);
            uint32 slot = atomicAdd(&pos[b], 1u);
            if (slot < CAP) sorted[(size_t)b * CAP + slot] = (dl << 20) | (uint32)s.w;
        }
    }
}

// ---------------------------------------------------------------------------
// Phase 2: one WG owns one bucket. LDS-accumulate x[src] into acc[dst_local],
// then fused relu + global_mean_pool partial sums (batch is sorted ->
// wave-uniform shuffle reduce, 1 atomic per wave).
// ---------------------------------------------------------------------------
__global__ __launch_bounds__(1024)
void bucket_reduce(const uint32* __restrict__ sorted,
                   const uint32* __restrict__ gpos,
                   const float* __restrict__ x,
                   const int* __restrict__ batch,
                   float* __restrict__ sums,
                   float* __restrict__ counts) {
    __shared__ float acc[BUCKET_NODES];
    const int b = blockIdx.x;
    const int tid = threadIdx.x;

    for (int n = tid; n < BUCKET_NODES; n += 1024) acc[n] = 0.0f;
    __syncthreads();

    uint32 cnt = gpos[b];
    if (cnt > CAP) cnt = CAP;
    const uint32* reg = sorted + (size_t)b * CAP;   // CAP%4==0 -> 16B aligned
    const vuint4* r4 = (const vuint4*)reg;
    const uint32 nvec = cnt / 4;

    for (uint32 i = tid; i < nvec; i += 1024) {
        vuint4 v = r4[i];
        atomicAdd(&acc[v.x >> 20], x[v.x & 0xFFFFFu]);
        atomicAdd(&acc[v.y >> 20], x[v.y & 0xFFFFFu]);
        atomicAdd(&acc[v.z >> 20], x[v.z & 0xFFFFFu]);
        atomicAdd(&acc[v.w >> 20], x[v.w & 0xFFFFFu]);
    }
    for (uint32 i = nvec * 4 + tid; i < cnt; i += 1024) {
        uint32 v = reg[i];
        atomicAdd(&acc[v >> 20], x[v & 0xFFFFFu]);
    }
    __syncthreads();

    const int node0 = b << BUCKET_SHIFT;
    for (int n = tid; n < BUCKET_NODES; n += 1024) {
        int i = node0 + n;
        float h = 0.0f;
        int g = -1;
        if (i < N_NODES) {
            h = fmaxf(acc[n], 0.0f);
            g = batch[i];
        }
        int g0 = __shfl(g, 0);
        if (__all(g == g0)) {
            #pragma unroll
            for (int off = 32; off > 0; off >>= 1)
                h += __shfl_down(h, off);
            if ((tid & 63) == 0 && g0 >= 0) {
                atomicAdd(&sums[g0], h);
                atomicAdd(&counts[g0], 64.0f);
            }
        } else if (g >= 0) {
            atomicAdd(&sums[g], h);
            atomicAdd(&counts[g], 1.0f);
        }
    }
}

// Stage 3: out[g] = (sums[g] / max(counts[g],1)) * W + b
__global__ void finalize_kernel(const float* __restrict__ sums,
                                const float* __restrict__ counts,
                                const float* __restrict__ W,
                                const float* __restrict__ b,
                                float* __restrict__ out) {
    int g = blockIdx.x * blockDim.x + threadIdx.x;
    if (g < NUM_GRAPHS) {
        float pooled = sums[g] / fmaxf(counts[g], 1.0f);
        out[g] = pooled * W[0] + b[0];
    }
}

// ---------------------------------------------------------------------------
// Fallback path (ws too small): known-passing device-atomic scatter.
// ---------------------------------------------------------------------------
__global__ void scatter_edges_dev(const vint4* __restrict__ src4,
                                  const vint4* __restrict__ dst4,
                                  const float* __restrict__ x,
                                  float* __restrict__ agg) {
    int t = blockIdx.x * blockDim.x + threadIdx.x;
    if (t < N_EDGES / 4) {
        vint4 s = __builtin_nontemporal_load(&src4[t]);
        vint4 d = __builtin_nontemporal_load(&dst4[t]);
        atomicAdd(&agg[d.x], x[s.x]);
        atomicAdd(&agg[d.y], x[s.y]);
        atomicAdd(&agg[d.z], x[s.z]);
        atomicAdd(&agg[d.w], x[s.w]);
    }
}

__global__ void pool_nodes_kernel(const float* __restrict__ agg,
                                  const int* __restrict__ batch,
                                  float* __restrict__ sums,
                                  float* __restrict__ counts) {
    int i = blockIdx.x * blockDim.x + threadIdx.x;
    float h = 0.0f;
    int g = -1;
    if (i < N_NODES) {
        h = fmaxf(agg[i], 0.0f);
        g = batch[i];
    }
    int g0 = __shfl(g, 0);
    if (__all(g == g0)) {
        #pragma unroll
        for (int off = 32; off > 0; off >>= 1)
            h += __shfl_down(h, off);
        if ((threadIdx.x & 63) == 0 && g0 >= 0) {
            atomicAdd(&sums[g0], h);
            atomicAdd(&counts[g0], 64.0f);
        }
    } else if (g >= 0) {
        atomicAdd(&sums[g], h);
        atomicAdd(&counts[g], 1.0f);
    }
}

extern "C" void kernel_launch(void* const* d_in, const int* in_sizes, int n_in,
                              void* d_out, int out_size, void* d_ws, size_t ws_size,
                              hipStream_t stream) {
    const float* x     = (const float*)d_in[0];
    const float* W     = (const float*)d_in[1];
    const float* b     = (const float*)d_in[2];
    const int*   edge  = (const int*)d_in[3];   // [2, N_EDGES] int32
    const int*   batch = (const int*)d_in[4];   // [N_NODES] int32, sorted
    float* out = (float*)d_out;

    const int* src = edge;             // row 0
    const int* dst = edge + N_EDGES;   // row 1

    const size_t sorted_elems = (size_t)NBUCKETS * CAP;        // 33,367,040 u32
    const size_t need = (sorted_elems + 256 + 2 * NUM_GRAPHS) * 4;

    if (ws_size >= need) {
        uint32* sorted = (uint32*)d_ws;
        uint32* gpos   = sorted + sorted_elems;
        float*  sums   = (float*)(gpos + 256);
        float*  counts = sums + NUM_GRAPHS;

        // zero only the control region: gpos(256) + sums(1024) + counts(1024)
        (void)hipMemsetAsync(gpos, 0, (256 + 2 * NUM_GRAPHS) * 4, stream);

        bucket_scatter<<<NCHUNK, 1024, 0, stream>>>(src, dst, sorted, gpos);
        bucket_reduce<<<NBUCKETS, 1024, 0, stream>>>(sorted, gpos, x, batch, sums, counts);
        finalize_kernel<<<(NUM_GRAPHS + 255) / 256, 256, 0, stream>>>(sums, counts, W, b, out);
    } else {
        // Fallback: device-atomic scatter (slow but correct)
        float* agg    = (float*)d_ws;
        float* sums   = agg + N_NODES;
        float* counts = sums + NUM_GRAPHS;
        (void)hipMemsetAsync(d_ws, 0, ((size_t)N_NODES + 2 * NUM_GRAPHS) * 4, stream);

        int nthreads = N_EDGES / 4;
        scatter_edges_dev<<<(nthreads + 255) / 256, 256, 0, stream>>>(
            (const vint4*)src, (const vint4*)dst, x, agg);
        pool_nodes_kernel<<<(N_NODES + 255) / 256, 256, 0, stream>>>(agg, batch, sums, counts);
        finalize_kernel<<<(NUM_GRAPHS + 255) / 256, 256, 0, stream>>>(sums, counts, W, b, out);
    }
}

// Round 5
// 732.836 us; speedup vs baseline: 2.5866x; 1.0716x over previous
//
#include <hip/hip_runtime.h>

#define N_NODES    1000000
#define N_EDGES    32000000
#define NUM_GRAPHS 1024

typedef int          vint4  __attribute__((ext_vector_type(4)));
typedef unsigned int uint32;
typedef unsigned int vuint4 __attribute__((ext_vector_type(4)));

#define BUCKET_SHIFT 12
#define BUCKET_NODES (1 << BUCKET_SHIFT)          // 4096 nodes/bucket
#define NBUCKETS     245                          // ceil(1e6 / 4096)

// ---- Tier 1: slab + LDS-staged line flush ----------------------------------
#define T1_NCHUNK   512
#define T1_BLOCK    512
#define T1_EDGES_PER_CHUNK (N_EDGES / T1_NCHUNK)  // 62500
#define T1_PAIRS    (T1_EDGES_PER_CHUNK / 2)      // 31250
#define T1_ROUNDS   ((T1_PAIRS + T1_BLOCK - 1) / T1_BLOCK)  // 62
#define SCAP        36                            // LDS staging slots per bucket
#define SLAB_CAP    368                           // per-cell slots: mean 256 + 7 sigma, %16==0

// ---- Tier 2 (known-good round-4 path) ---------------------------------------
#define T2_CAP      136192
#define T2_NCHUNK   512
#define T2_EPC      (N_EDGES / T2_NCHUNK)

// ============================================================================
// Tier 1 scatter: per WG owns a 62500-edge chunk. Rounds of 1024 edges:
//   p1: LDS round-histogram; p2: claim staging slot (LDS atomic) and stage,
//   or (rare overflow) store direct to slab tail; p3: flush complete 16-entry
//   (64B) lines coalesced to the cell's slab region, compact remainder.
// No global atomics; stores are full-line sequential.
// ============================================================================
__global__ __launch_bounds__(T1_BLOCK)
void slab_scatter(const int* __restrict__ src,
                  const int* __restrict__ dst,
                  uint32* __restrict__ slab,
                  uint32* __restrict__ fcnt_g,
                  uint32* __restrict__ ecnt_g) {
    __shared__ uint32 stage[NBUCKETS][SCAP];
    __shared__ uint32 rhist[NBUCKETS];
    __shared__ uint32 rpos[NBUCKETS];
    __shared__ uint32 ecnt[NBUCKETS];
    __shared__ uint32 flushed[NBUCKETS];
    __shared__ uint32 carry[NBUCKETS];

    const int tid = threadIdx.x;
    const int w   = blockIdx.x;
    const size_t ebase = (size_t)w * T1_EDGES_PER_CHUNK;   // byte offset %8==0
    const int2* d2 = (const int2*)(dst + ebase);
    const int2* s2 = (const int2*)(src + ebase);

    for (int b = tid; b < NBUCKETS; b += T1_BLOCK) {
        rhist[b] = 0; rpos[b] = 0; ecnt[b] = 0; flushed[b] = 0; carry[b] = 0;
    }
    __syncthreads();

    const int grp    = tid >> 4;    // 32 groups of 16 lanes
    const int lane16 = tid & 15;

    for (int r = 0; r < T1_ROUNDS; ++r) {
        int p = r * T1_BLOCK + tid;
        int b0 = -1, b1 = -1; uint32 v0 = 0, v1 = 0;
        if (p < T1_PAIRS) {
            int2 d = d2[p];
            int2 s = s2[p];
            b0 = (uint32)d.x >> BUCKET_SHIFT;
            v0 = (((uint32)d.x & (BUCKET_NODES - 1)) << 20) | (uint32)s.x;
            b1 = (uint32)d.y >> BUCKET_SHIFT;
            v1 = (((uint32)d.y & (BUCKET_NODES - 1)) << 20) | (uint32)s.y;
            atomicAdd(&rhist[b0], 1u);
            atomicAdd(&rhist[b1], 1u);
        }
        __syncthreads();
        if (p < T1_PAIRS) {
            // edge 0
            if (carry[b0] + rhist[b0] <= SCAP) {
                uint32 c = atomicAdd(&rpos[b0], 1u);
                stage[b0][carry[b0] + c] = v0;
            } else {
                uint32 e = atomicAdd(&ecnt[b0], 1u);
                slab[((size_t)b0 * T1_NCHUNK + w) * SLAB_CAP + (SLAB_CAP - 1 - e)] = v0;
            }
            // edge 1
            if (carry[b1] + rhist[b1] <= SCAP) {
                uint32 c = atomicAdd(&rpos[b1], 1u);
                stage[b1][carry[b1] + c] = v1;
            } else {
                uint32 e = atomicAdd(&ecnt[b1], 1u);
                slab[((size_t)b1 * T1_NCHUNK + w) * SLAB_CAP + (SLAB_CAP - 1 - e)] = v1;
            }
        }
        __syncthreads();
        // phase 3: flush complete lines; each 16-lane group owns buckets grp, grp+32, ...
        for (int b = grp; b < NBUCKETS; b += 32) {
            uint32 car   = carry[b];
            uint32 tot   = car + rpos[b];
            uint32 lines = tot >> 4;
            uint32 rem   = tot & 15u;
            uint32 fl    = flushed[b];
            uint32* dp = slab + ((size_t)b * T1_NCHUNK + w) * SLAB_CAP + fl;
            for (uint32 l = 0; l < lines; ++l)
                dp[l * 16 + lane16] = stage[b][l * 16 + lane16];   // 64B coalesced
            if (lines) {
                uint32 mv = 0;
                if (lane16 < rem) mv = stage[b][lines * 16 + lane16];
                if (lane16 < rem) stage[b][lane16] = mv;           // compact remainder
            }
            if (lane16 == 0) {
                flushed[b] = fl + lines * 16;
                carry[b]   = rem;
                rpos[b]    = 0;
                rhist[b]   = 0;
            }
        }
        __syncthreads();
    }
    // epilogue: flush partial remainder, publish per-cell counts
    for (int b = grp; b < NBUCKETS; b += 32) {
        uint32 rem = carry[b];
        uint32 fl  = flushed[b];
        uint32* dp = slab + ((size_t)b * T1_NCHUNK + w) * SLAB_CAP + fl;
        if (lane16 < rem) dp[lane16] = stage[b][lane16];
        if (lane16 == 0) {
            fcnt_g[(size_t)b * T1_NCHUNK + w] = fl + rem;
            ecnt_g[(size_t)b * T1_NCHUNK + w] = ecnt[b];
        }
    }
}

// ============================================================================
// Tier 1 reduce: one WG per bucket. Stream the bucket's 512 cell segments
// (coalesced), LDS-accumulate x[src], then fused relu + sorted-batch pooling.
// ============================================================================
__global__ __launch_bounds__(1024)
void slab_reduce(const uint32* __restrict__ slab,
                 const uint32* __restrict__ fcnt_g,
                 const uint32* __restrict__ ecnt_g,
                 const float* __restrict__ x,
                 const int* __restrict__ batch,
                 float* __restrict__ sums,
                 float* __restrict__ counts) {
    __shared__ float acc[BUCKET_NODES];
    const int b = blockIdx.x;
    const int tid = threadIdx.x;
    for (int n = tid; n < BUCKET_NODES; n += 1024) acc[n] = 0.0f;
    __syncthreads();

    const int wv = tid >> 6, lane = tid & 63;
    for (int w = wv; w < T1_NCHUNK; w += 16) {
        size_t cell = (size_t)b * T1_NCHUNK + w;
        uint32 fc = fcnt_g[cell];
        uint32 ec = ecnt_g[cell];
        const uint32* base = slab + cell * SLAB_CAP;
        for (uint32 i = lane; i < fc; i += 64) {
            uint32 v = base[i];
            atomicAdd(&acc[v >> 20], x[v & 0xFFFFFu]);
        }
        for (uint32 i = lane; i < ec; i += 64) {
            uint32 v = base[SLAB_CAP - 1 - i];
            atomicAdd(&acc[v >> 20], x[v & 0xFFFFFu]);
        }
    }
    __syncthreads();

    const int node0 = b << BUCKET_SHIFT;
    for (int n = tid; n < BUCKET_NODES; n += 1024) {
        int i = node0 + n;
        float h = 0.0f;
        int g = -1;
        if (i < N_NODES) {
            h = fmaxf(acc[n], 0.0f);
            g = batch[i];
        }
        int g0 = __shfl(g, 0);
        if (__all(g == g0)) {
            #pragma unroll
            for (int off = 32; off > 0; off >>= 1)
                h += __shfl_down(h, off);
            if ((tid & 63) == 0 && g0 >= 0) {
                atomicAdd(&sums[g0], h);
                atomicAdd(&counts[g0], 64.0f);
            }
        } else if (g >= 0) {
            atomicAdd(&sums[g], h);
            atomicAdd(&counts[g], 1.0f);
        }
    }
}

// Stage 3: out[g] = (sums[g] / max(counts[g],1)) * W + b
__global__ void finalize_kernel(const float* __restrict__ sums,
                                const float* __restrict__ counts,
                                const float* __restrict__ W,
                                const float* __restrict__ b,
                                float* __restrict__ out) {
    int g = blockIdx.x * blockDim.x + threadIdx.x;
    if (g < NUM_GRAPHS) {
        float pooled = sums[g] / fmaxf(counts[g], 1.0f);
        out[g] = pooled * W[0] + b[0];
    }
}

// ============================================================================
// Tier 2: round-4 known-good path (atomic block reservation + random stores)
// ============================================================================
__global__ __launch_bounds__(1024)
void bucket_scatter(const int* __restrict__ src,
                    const int* __restrict__ dst,
                    uint32* __restrict__ sorted,
                    uint32* __restrict__ gpos) {
    __shared__ uint32 hist[NBUCKETS];
    __shared__ uint32 pos[NBUCKETS];
    const int tid = threadIdx.x;
    const size_t base = (size_t)blockIdx.x * T2_EPC;
    for (int b = tid; b < NBUCKETS; b += 1024) hist[b] = 0;
    __syncthreads();
    const vint4* d4 = (const vint4*)(dst + base);
    const vint4* s4 = (const vint4*)(src + base);
    const int nvec = T2_EPC / 4;
    for (int i = tid; i < nvec; i += 1024) {
        vint4 d = d4[i];
        atomicAdd(&hist[(uint32)d.x >> BUCKET_SHIFT], 1u);
        atomicAdd(&hist[(uint32)d.y >> BUCKET_SHIFT], 1u);
        atomicAdd(&hist[(uint32)d.z >> BUCKET_SHIFT], 1u);
        atomicAdd(&hist[(uint32)d.w >> BUCKET_SHIFT], 1u);
    }
    __syncthreads();
    for (int b = tid; b < NBUCKETS; b += 1024)
        pos[b] = atomicAdd(&gpos[b], hist[b]);
    __syncthreads();
    for (int i = tid; i < nvec; i += 1024) {
        vint4 d = d4[i];
        vint4 s = s4[i];
        {
            uint32 dd = (uint32)d.x, b = dd >> BUCKET_SHIFT, dl = dd & (BUCKET_NODES - 1);
            uint32 slot = atomicAdd(&pos[b], 1u);
            if (slot < T2_CAP) sorted[(size_t)b * T2_CAP + slot] = (dl << 20) | (uint32)s.x;
        }
        {
            uint32 dd = (uint32)d.y, b = dd >> BUCKET_SHIFT, dl = dd & (BUCKET_NODES - 1);
            uint32 slot = atomicAdd(&pos[b], 1u);
            if (slot < T2_CAP) sorted[(size_t)b * T2_CAP + slot] = (dl << 20) | (uint32)s.y;
        }
        {
            uint32 dd = (uint32)d.z, b = dd >> BUCKET_SHIFT, dl = dd & (BUCKET_NODES - 1);
            uint32 slot = atomicAdd(&pos[b], 1u);
            if (slot < T2_CAP) sorted[(size_t)b * T2_CAP + slot] = (dl << 20) | (uint32)s.z;
        }
        {
            uint32 dd = (uint32)d.w, b = dd >> BUCKET_SHIFT, dl = dd & (BUCKET_NODES - 1);
            uint32 slot = atomicAdd(&pos[b], 1u);
            if (slot < T2_CAP) sorted[(size_t)b * T2_CAP + slot] = (dl << 20) | (uint32)s.w;
        }
    }
}

__global__ __launch_bounds__(1024)
void bucket_reduce(const uint32* __restrict__ sorted,
                   const uint32* __restrict__ gpos,
                   const float* __restrict__ x,
                   const int* __restrict__ batch,
                   float* __restrict__ sums,
                   float* __restrict__ counts) {
    __shared__ float acc[BUCKET_NODES];
    const int b = blockIdx.x;
    const int tid = threadIdx.x;
    for (int n = tid; n < BUCKET_NODES; n += 1024) acc[n] = 0.0f;
    __syncthreads();
    uint32 cnt = gpos[b];
    if (cnt > T2_CAP) cnt = T2_CAP;
    const uint32* reg = sorted + (size_t)b * T2_CAP;
    const vuint4* r4 = (const vuint4*)reg;
    const uint32 nvec = cnt / 4;
    for (uint32 i = tid; i < nvec; i += 1024) {
        vuint4 v = r4[i];
        atomicAdd(&acc[v.x >> 20], x[v.x & 0xFFFFFu]);
        atomicAdd(&acc[v.y >> 20], x[v.y & 0xFFFFFu]);
        atomicAdd(&acc[v.z >> 20], x[v.z & 0xFFFFFu]);
        atomicAdd(&acc[v.w >> 20], x[v.w & 0xFFFFFu]);
    }
    for (uint32 i = nvec * 4 + tid; i < cnt; i += 1024) {
        uint32 v = reg[i];
        atomicAdd(&acc[v >> 20], x[v & 0xFFFFFu]);
    }
    __syncthreads();
    const int node0 = b << BUCKET_SHIFT;
    for (int n = tid; n < BUCKET_NODES; n += 1024) {
        int i = node0 + n;
        float h = 0.0f;
        int g = -1;
        if (i < N_NODES) {
            h = fmaxf(acc[n], 0.0f);
            g = batch[i];
        }
        int g0 = __shfl(g, 0);
        if (__all(g == g0)) {
            #pragma unroll
            for (int off = 32; off > 0; off >>= 1)
                h += __shfl_down(h, off);
            if ((tid & 63) == 0 && g0 >= 0) {
                atomicAdd(&sums[g0], h);
                atomicAdd(&counts[g0], 64.0f);
            }
        } else if (g >= 0) {
            atomicAdd(&sums[g], h);
            atomicAdd(&counts[g], 1.0f);
        }
    }
}

// Tier 3 fallback: device-atomic scatter (slow but correct)
__global__ void scatter_edges_dev(const vint4* __restrict__ src4,
                                  const vint4* __restrict__ dst4,
                                  const float* __restrict__ x,
                                  float* __restrict__ agg) {
    int t = blockIdx.x * blockDim.x + threadIdx.x;
    if (t < N_EDGES / 4) {
        vint4 s = __builtin_nontemporal_load(&src4[t]);
        vint4 d = __builtin_nontemporal_load(&dst4[t]);
        atomicAdd(&agg[d.x], x[s.x]);
        atomicAdd(&agg[d.y], x[s.y]);
        atomicAdd(&agg[d.z], x[s.z]);
        atomicAdd(&agg[d.w], x[s.w]);
    }
}

__global__ void pool_nodes_kernel(const float* __restrict__ agg,
                                  const int* __restrict__ batch,
                                  float* __restrict__ sums,
                                  float* __restrict__ counts) {
    int i = blockIdx.x * blockDim.x + threadIdx.x;
    float h = 0.0f;
    int g = -1;
    if (i < N_NODES) {
        h = fmaxf(agg[i], 0.0f);
        g = batch[i];
    }
    int g0 = __shfl(g, 0);
    if (__all(g == g0)) {
        #pragma unroll
        for (int off = 32; off > 0; off >>= 1)
            h += __shfl_down(h, off);
        if ((threadIdx.x & 63) == 0 && g0 >= 0) {
            atomicAdd(&sums[g0], h);
            atomicAdd(&counts[g0], 64.0f);
        }
    } else if (g >= 0) {
        atomicAdd(&sums[g], h);
        atomicAdd(&counts[g], 1.0f);
    }
}

extern "C" void kernel_launch(void* const* d_in, const int* in_sizes, int n_in,
                              void* d_out, int out_size, void* d_ws, size_t ws_size,
                              hipStream_t stream) {
    const float* x     = (const float*)d_in[0];
    const float* W     = (const float*)d_in[1];
    const float* b     = (const float*)d_in[2];
    const int*   edge  = (const int*)d_in[3];   // [2, N_EDGES] int32
    const int*   batch = (const int*)d_in[4];   // [N_NODES] int32, sorted
    float* out = (float*)d_out;

    const int* src = edge;             // row 0
    const int* dst = edge + N_EDGES;   // row 1

    const size_t ncells     = (size_t)NBUCKETS * T1_NCHUNK;           // 125440
    const size_t slab_elems = ncells * SLAB_CAP;                      // 46,161,920
    const size_t need1 = (slab_elems + 2 * ncells + 2 * NUM_GRAPHS) * 4;
    const size_t t2_elems = (size_t)NBUCKETS * T2_CAP;                // 33,367,040
    const size_t need2 = (t2_elems + 256 + 2 * NUM_GRAPHS) * 4;

    if (ws_size >= need1) {
        uint32* slab   = (uint32*)d_ws;
        uint32* fcnt_g = slab + slab_elems;
        uint32* ecnt_g = fcnt_g + ncells;
        float*  sums   = (float*)(ecnt_g + ncells);
        float*  counts = sums + NUM_GRAPHS;
        (void)hipMemsetAsync(sums, 0, 2 * NUM_GRAPHS * 4, stream);

        slab_scatter<<<T1_NCHUNK, T1_BLOCK, 0, stream>>>(src, dst, slab, fcnt_g, ecnt_g);
        slab_reduce<<<NBUCKETS, 1024, 0, stream>>>(slab, fcnt_g, ecnt_g, x, batch, sums, counts);
        finalize_kernel<<<(NUM_GRAPHS + 255) / 256, 256, 0, stream>>>(sums, counts, W, b, out);
    } else if (ws_size >= need2) {
        uint32* sorted = (uint32*)d_ws;
        uint32* gpos   = sorted + t2_elems;
        float*  sums   = (float*)(gpos + 256);
        float*  counts = sums + NUM_GRAPHS;
        (void)hipMemsetAsync(gpos, 0, (256 + 2 * NUM_GRAPHS) * 4, stream);

        bucket_scatter<<<T2_NCHUNK, 1024, 0, stream>>>(src, dst, sorted, gpos);
        bucket_reduce<<<NBUCKETS, 1024, 0, stream>>>(sorted, gpos, x, batch, sums, counts);
        finalize_kernel<<<(NUM_GRAPHS + 255) / 256, 256, 0, stream>>>(sums, counts, W, b, out);
    } else {
        float* agg    = (float*)d_ws;
        float* sums   = agg + N_NODES;
        float* counts = sums + NUM_GRAPHS;
        (void)hipMemsetAsync(d_ws, 0, ((size_t)N_NODES + 2 * NUM_GRAPHS) * 4, stream);

        int nthreads = N_EDGES / 4;
        scatter_edges_dev<<<(nthreads + 255) / 256, 256, 0, stream>>>(
            (const vint4*)src, (const vint4*)dst, x, agg);
        pool_nodes_kernel<<<(N_NODES + 255) / 256, 256, 0, stream>>>(agg, batch, sums, counts);
        finalize_kernel<<<(NUM_GRAPHS + 255) / 256, 256, 0, stream>>>(sums, counts, W, b, out);
    }
}

// Round 6
// 622.928 us; speedup vs baseline: 3.0430x; 1.1764x over previous
//
#include <hip/hip_runtime.h>

#define N_NODES    1000000
#define N_EDGES    32000000
#define NUM_GRAPHS 1024

typedef int          vint4  __attribute__((ext_vector_type(4)));
typedef unsigned int uint32;
typedef unsigned int vuint4 __attribute__((ext_vector_type(4)));

#define BUCKET_SHIFT 12
#define BUCKET_NODES (1 << BUCKET_SHIFT)          // 4096 nodes/bucket
#define NBUCKETS     245                          // ceil(1e6 / 4096)

// ---- Tier 1: slab + LDS-staged line flush ----------------------------------
#define T1_NCHUNK   512
#define T1_BLOCK    512
#define T1_EDGES_PER_CHUNK (N_EDGES / T1_NCHUNK)  // 62500
#define T1_QUADS    (T1_EDGES_PER_CHUNK / 4)      // 15625
#define T1_ROUNDS   ((T1_QUADS + T1_BLOCK - 1) / T1_BLOCK)  // 31
#define SCAP        64                            // LDS staging slots per bucket (4 lines)
#define SLAB_CAP    368                           // per-cell slots: mean 256 + 7 sigma, %16==0

// ---- Tier 2 (known-good round-4 path) ---------------------------------------
#define T2_CAP      136192
#define T2_NCHUNK   512
#define T2_EPC      (N_EDGES / T2_NCHUNK)

// ============================================================================
// Tier 1 scatter v2: no histogram pass. Rounds of 2048 edges (4/thread):
//   phase A: claim staging slot via LDS atomic; index < SCAP -> stage in LDS,
//            else (≈never) direct store to slab tail.
//   phase B: flush complete 16-entry (64B) lines coalesced, compact remainder.
// 2 syncs/round, 1 LDS atomic/edge, full-line global stores.
// ============================================================================
__global__ __launch_bounds__(T1_BLOCK)
void slab_scatter(const int* __restrict__ src,
                  const int* __restrict__ dst,
                  uint32* __restrict__ slab,
                  uint32* __restrict__ fcnt_g,
                  uint32* __restrict__ ecnt_g) {
    __shared__ uint32 stage[NBUCKETS][SCAP];
    __shared__ uint32 rpos[NBUCKETS];     // claims this round
    __shared__ uint32 ecnt[NBUCKETS];     // tail (overflow) count
    __shared__ uint32 flushed[NBUCKETS];  // front entries already in slab
    __shared__ uint32 carry[NBUCKETS];    // staged entries carried across rounds

    const int tid = threadIdx.x;
    const int w   = blockIdx.x;
    const vint4* d4 = (const vint4*)(dst + (size_t)w * T1_EDGES_PER_CHUNK);
    const vint4* s4 = (const vint4*)(src + (size_t)w * T1_EDGES_PER_CHUNK);

    for (int b = tid; b < NBUCKETS; b += T1_BLOCK) {
        rpos[b] = 0; ecnt[b] = 0; flushed[b] = 0; carry[b] = 0;
    }
    __syncthreads();

    const int grp    = tid >> 4;    // 32 groups of 16 lanes
    const int lane16 = tid & 15;

    for (int r = 0; r < T1_ROUNDS; ++r) {
        int q = r * T1_BLOCK + tid;
        if (q < T1_QUADS) {
            vint4 d = d4[q];
            vint4 s = s4[q];
            #pragma unroll
            for (int k = 0; k < 4; ++k) {
                uint32 dd = (uint32)(k == 0 ? d.x : k == 1 ? d.y : k == 2 ? d.z : d.w);
                uint32 ss = (uint32)(k == 0 ? s.x : k == 1 ? s.y : k == 2 ? s.z : s.w);
                uint32 b  = dd >> BUCKET_SHIFT;
                uint32 v  = ((dd & (BUCKET_NODES - 1)) << 20) | ss;
                uint32 c  = carry[b] + atomicAdd(&rpos[b], 1u);
                if (c < SCAP) {
                    stage[b][c] = v;
                } else {
                    uint32 e = atomicAdd(&ecnt[b], 1u);
                    slab[((size_t)b * T1_NCHUNK + w) * SLAB_CAP + (SLAB_CAP - 1 - e)] = v;
                }
            }
        }
        __syncthreads();
        // phase B: flush complete lines; 16-lane group owns buckets grp, grp+32, ...
        for (int b = grp; b < NBUCKETS; b += 32) {
            uint32 tot = carry[b] + rpos[b];
            if (tot > SCAP) tot = SCAP;
            uint32 lines = tot >> 4;
            uint32 rem   = tot & 15u;
            uint32 fl    = flushed[b];
            uint32* dp = slab + ((size_t)b * T1_NCHUNK + w) * SLAB_CAP + fl;
            for (uint32 l = 0; l < lines; ++l)
                dp[l * 16 + lane16] = stage[b][l * 16 + lane16];   // 64B coalesced
            if (lines) {
                uint32 mv = 0;
                if (lane16 < rem) mv = stage[b][lines * 16 + lane16];
                if (lane16 < rem) stage[b][lane16] = mv;           // compact remainder
            }
            if (lane16 == 0) {
                flushed[b] = fl + lines * 16;
                carry[b]   = rem;
                rpos[b]    = 0;
            }
        }
        __syncthreads();
    }
    // epilogue: flush partial remainder, publish per-cell counts
    for (int b = grp; b < NBUCKETS; b += 32) {
        uint32 rem = carry[b];
        uint32 fl  = flushed[b];
        uint32* dp = slab + ((size_t)b * T1_NCHUNK + w) * SLAB_CAP + fl;
        if (lane16 < rem) dp[lane16] = stage[b][lane16];
        if (lane16 == 0) {
            fcnt_g[(size_t)b * T1_NCHUNK + w] = fl + rem;
            ecnt_g[(size_t)b * T1_NCHUNK + w] = ecnt[b];
        }
    }
}

// ============================================================================
// Tier 1 reduce: one WG per bucket. Stream the bucket's 512 cell segments
// (vectorized, coalesced), LDS-accumulate x[src], then fused relu + pooling.
// ============================================================================
__global__ __launch_bounds__(1024)
void slab_reduce(const uint32* __restrict__ slab,
                 const uint32* __restrict__ fcnt_g,
                 const uint32* __restrict__ ecnt_g,
                 const float* __restrict__ x,
                 const int* __restrict__ batch,
                 float* __restrict__ sums,
                 float* __restrict__ counts) {
    __shared__ float acc[BUCKET_NODES];
    const int b = blockIdx.x;
    const int tid = threadIdx.x;
    for (int n = tid; n < BUCKET_NODES; n += 1024) acc[n] = 0.0f;
    __syncthreads();

    const int wv = tid >> 6, lane = tid & 63;
    for (int w = wv; w < T1_NCHUNK; w += 16) {
        size_t cell = (size_t)b * T1_NCHUNK + w;
        uint32 fc = fcnt_g[cell];
        uint32 ec = ecnt_g[cell];
        const uint32* base = slab + cell * SLAB_CAP;     // 16B aligned (SLAB_CAP%4==0)
        const vuint4* b4 = (const vuint4*)base;
        uint32 nq = fc >> 2;
        for (uint32 i = lane; i < nq; i += 64) {
            vuint4 v = b4[i];
            atomicAdd(&acc[v.x >> 20], x[v.x & 0xFFFFFu]);
            atomicAdd(&acc[v.y >> 20], x[v.y & 0xFFFFFu]);
            atomicAdd(&acc[v.z >> 20], x[v.z & 0xFFFFFu]);
            atomicAdd(&acc[v.w >> 20], x[v.w & 0xFFFFFu]);
        }
        for (uint32 i = nq * 4 + lane; i < fc; i += 64) {
            uint32 v = base[i];
            atomicAdd(&acc[v >> 20], x[v & 0xFFFFFu]);
        }
        for (uint32 i = lane; i < ec; i += 64) {
            uint32 v = base[SLAB_CAP - 1 - i];
            atomicAdd(&acc[v >> 20], x[v & 0xFFFFFu]);
        }
    }
    __syncthreads();

    const int node0 = b << BUCKET_SHIFT;
    for (int n = tid; n < BUCKET_NODES; n += 1024) {
        int i = node0 + n;
        float h = 0.0f;
        int g = -1;
        if (i < N_NODES) {
            h = fmaxf(acc[n], 0.0f);
            g = batch[i];
        }
        int g0 = __shfl(g, 0);
        if (__all(g == g0)) {
            #pragma unroll
            for (int off = 32; off > 0; off >>= 1)
                h += __shfl_down(h, off);
            if ((tid & 63) == 0 && g0 >= 0) {
                atomicAdd(&sums[g0], h);
                atomicAdd(&counts[g0], 64.0f);
            }
        } else if (g >= 0) {
            atomicAdd(&sums[g], h);
            atomicAdd(&counts[g], 1.0f);
        }
    }
}

// Stage 3: out[g] = (sums[g] / max(counts[g],1)) * W + b
__global__ void finalize_kernel(const float* __restrict__ sums,
                                const float* __restrict__ counts,
                                const float* __restrict__ W,
                                const float* __restrict__ b,
                                float* __restrict__ out) {
    int g = blockIdx.x * blockDim.x + threadIdx.x;
    if (g < NUM_GRAPHS) {
        float pooled = sums[g] / fmaxf(counts[g], 1.0f);
        out[g] = pooled * W[0] + b[0];
    }
}

// ============================================================================
// Tier 2: round-4 known-good path (atomic block reservation + random stores)
// ============================================================================
__global__ __launch_bounds__(1024)
void bucket_scatter(const int* __restrict__ src,
                    const int* __restrict__ dst,
                    uint32* __restrict__ sorted,
                    uint32* __restrict__ gpos) {
    __shared__ uint32 hist[NBUCKETS];
    __shared__ uint32 pos[NBUCKETS];
    const int tid = threadIdx.x;
    const size_t base = (size_t)blockIdx.x * T2_EPC;
    for (int b = tid; b < NBUCKETS; b += 1024) hist[b] = 0;
    __syncthreads();
    const vint4* d4 = (const vint4*)(dst + base);
    const vint4* s4 = (const vint4*)(src + base);
    const int nvec = T2_EPC / 4;
    for (int i = tid; i < nvec; i += 1024) {
        vint4 d = d4[i];
        atomicAdd(&hist[(uint32)d.x >> BUCKET_SHIFT], 1u);
        atomicAdd(&hist[(uint32)d.y >> BUCKET_SHIFT], 1u);
        atomicAdd(&hist[(uint32)d.z >> BUCKET_SHIFT], 1u);
        atomicAdd(&hist[(uint32)d.w >> BUCKET_SHIFT], 1u);
    }
    __syncthreads();
    for (int b = tid; b < NBUCKETS; b += 1024)
        pos[b] = atomicAdd(&gpos[b], hist[b]);
    __syncthreads();
    for (int i = tid; i < nvec; i += 1024) {
        vint4 d = d4[i];
        vint4 s = s4[i];
        #pragma unroll
        for (int k = 0; k < 4; ++k) {
            uint32 dd = (uint32)(k == 0 ? d.x : k == 1 ? d.y : k == 2 ? d.z : d.w);
            uint32 ss = (uint32)(k == 0 ? s.x : k == 1 ? s.y : k == 2 ? s.z : s.w);
            uint32 b = dd >> BUCKET_SHIFT, dl = dd & (BUCKET_NODES - 1);
            uint32 slot = atomicAdd(&pos[b], 1u);
            if (slot < T2_CAP) sorted[(size_t)b * T2_CAP + slot] = (dl << 20) | ss;
        }
    }
}

__global__ __launch_bounds__(1024)
void bucket_reduce(const uint32* __restrict__ sorted,
                   const uint32* __restrict__ gpos,
                   const float* __restrict__ x,
                   const int* __restrict__ batch,
                   float* __restrict__ sums,
                   float* __restrict__ counts) {
    __shared__ float acc[BUCKET_NODES];
    const int b = blockIdx.x;
    const int tid = threadIdx.x;
    for (int n = tid; n < BUCKET_NODES; n += 1024) acc[n] = 0.0f;
    __syncthreads();
    uint32 cnt = gpos[b];
    if (cnt > T2_CAP) cnt = T2_CAP;
    const uint32* reg = sorted + (size_t)b * T2_CAP;
    const vuint4* r4 = (const vuint4*)reg;
    const uint32 nvec = cnt / 4;
    for (uint32 i = tid; i < nvec; i += 1024) {
        vuint4 v = r4[i];
        atomicAdd(&acc[v.x >> 20], x[v.x & 0xFFFFFu]);
        atomicAdd(&acc[v.y >> 20], x[v.y & 0xFFFFFu]);
        atomicAdd(&acc[v.z >> 20], x[v.z & 0xFFFFFu]);
        atomicAdd(&acc[v.w >> 20], x[v.w & 0xFFFFFu]);
    }
    for (uint32 i = nvec * 4 + tid; i < cnt; i += 1024) {
        uint32 v = reg[i];
        atomicAdd(&acc[v >> 20], x[v & 0xFFFFFu]);
    }
    __syncthreads();
    const int node0 = b << BUCKET_SHIFT;
    for (int n = tid; n < BUCKET_NODES; n += 1024) {
        int i = node0 + n;
        float h = 0.0f;
        int g = -1;
        if (i < N_NODES) {
            h = fmaxf(acc[n], 0.0f);
            g = batch[i];
        }
        int g0 = __shfl(g, 0);
        if (__all(g == g0)) {
            #pragma unroll
            for (int off = 32; off > 0; off >>= 1)
                h += __shfl_down(h, off);
            if ((tid & 63) == 0 && g0 >= 0) {
                atomicAdd(&sums[g0], h);
                atomicAdd(&counts[g0], 64.0f);
            }
        } else if (g >= 0) {
            atomicAdd(&sums[g], h);
            atomicAdd(&counts[g], 1.0f);
        }
    }
}

// Tier 3 fallback: device-atomic scatter (slow but correct)
__global__ void scatter_edges_dev(const vint4* __restrict__ src4,
                                  const vint4* __restrict__ dst4,
                                  const float* __restrict__ x,
                                  float* __restrict__ agg) {
    int t = blockIdx.x * blockDim.x + threadIdx.x;
    if (t < N_EDGES / 4) {
        vint4 s = __builtin_nontemporal_load(&src4[t]);
        vint4 d = __builtin_nontemporal_load(&dst4[t]);
        atomicAdd(&agg[d.x], x[s.x]);
        atomicAdd(&agg[d.y], x[s.y]);
        atomicAdd(&agg[d.z], x[s.z]);
        atomicAdd(&agg[d.w], x[s.w]);
    }
}

__global__ void pool_nodes_kernel(const float* __restrict__ agg,
                                  const int* __restrict__ batch,
                                  float* __restrict__ sums,
                                  float* __restrict__ counts) {
    int i = blockIdx.x * blockDim.x + threadIdx.x;
    float h = 0.0f;
    int g = -1;
    if (i < N_NODES) {
        h = fmaxf(agg[i], 0.0f);
        g = batch[i];
    }
    int g0 = __shfl(g, 0);
    if (__all(g == g0)) {
        #pragma unroll
        for (int off = 32; off > 0; off >>= 1)
            h += __shfl_down(h, off);
        if ((threadIdx.x & 63) == 0 && g0 >= 0) {
            atomicAdd(&sums[g0], h);
            atomicAdd(&counts[g0], 64.0f);
        }
    } else if (g >= 0) {
        atomicAdd(&sums[g], h);
        atomicAdd(&counts[g], 1.0f);
    }
}

extern "C" void kernel_launch(void* const* d_in, const int* in_sizes, int n_in,
                              void* d_out, int out_size, void* d_ws, size_t ws_size,
                              hipStream_t stream) {
    const float* x     = (const float*)d_in[0];
    const float* W     = (const float*)d_in[1];
    const float* b     = (const float*)d_in[2];
    const int*   edge  = (const int*)d_in[3];   // [2, N_EDGES] int32
    const int*   batch = (const int*)d_in[4];   // [N_NODES] int32, sorted
    float* out = (float*)d_out;

    const int* src = edge;             // row 0
    const int* dst = edge + N_EDGES;   // row 1

    const size_t ncells     = (size_t)NBUCKETS * T1_NCHUNK;           // 125440
    const size_t slab_elems = ncells * SLAB_CAP;                      // 46,161,920
    const size_t need1 = (slab_elems + 2 * ncells + 2 * NUM_GRAPHS) * 4;
    const size_t t2_elems = (size_t)NBUCKETS * T2_CAP;                // 33,367,040
    const size_t need2 = (t2_elems + 256 + 2 * NUM_GRAPHS) * 4;

    if (ws_size >= need1) {
        uint32* slab   = (uint32*)d_ws;
        uint32* fcnt_g = slab + slab_elems;
        uint32* ecnt_g = fcnt_g + ncells;
        float*  sums   = (float*)(ecnt_g + ncells);
        float*  counts = sums + NUM_GRAPHS;
        (void)hipMemsetAsync(sums, 0, 2 * NUM_GRAPHS * 4, stream);

        slab_scatter<<<T1_NCHUNK, T1_BLOCK, 0, stream>>>(src, dst, slab, fcnt_g, ecnt_g);
        slab_reduce<<<NBUCKETS, 1024, 0, stream>>>(slab, fcnt_g, ecnt_g, x, batch, sums, counts);
        finalize_kernel<<<(NUM_GRAPHS + 255) / 256, 256, 0, stream>>>(sums, counts, W, b, out);
    } else if (ws_size >= need2) {
        uint32* sorted = (uint32*)d_ws;
        uint32* gpos   = sorted + t2_elems;
        float*  sums   = (float*)(gpos + 256);
        float*  counts = sums + NUM_GRAPHS;
        (void)hipMemsetAsync(gpos, 0, (256 + 2 * NUM_GRAPHS) * 4, stream);

        bucket_scatter<<<T2_NCHUNK, 1024, 0, stream>>>(src, dst, sorted, gpos);
        bucket_reduce<<<NBUCKETS, 1024, 0, stream>>>(sorted, gpos, x, batch, sums, counts);
        finalize_kernel<<<(NUM_GRAPHS + 255) / 256, 256, 0, stream>>>(sums, counts, W, b, out);
    } else {
        float* agg    = (float*)d_ws;
        float* sums   = agg + N_NODES;
        float* counts = sums + NUM_GRAPHS;
        (void)hipMemsetAsync(d_ws, 0, ((size_t)N_NODES + 2 * NUM_GRAPHS) * 4, stream);

        int nthreads = N_EDGES / 4;
        scatter_edges_dev<<<(nthreads + 255) / 256, 256, 0, stream>>>(
            (const vint4*)src, (const vint4*)dst, x, agg);
        pool_nodes_kernel<<<(N_NODES + 255) / 256, 256, 0, stream>>>(agg, batch, sums, counts);
        finalize_kernel<<<(NUM_GRAPHS + 255) / 256, 256, 0, stream>>>(sums, counts, W, b, out);
    }
}